// Round 3
// baseline (904.425 us; speedup 1.0000x reference)
//
#include <hip/hip_runtime.h>
#include <hip/hip_bf16.h>
#include <cmath>

// Problem constants (from reference): N=100000, D=512, H1=16, C=40, NNZ=3.2M
#define DD 512
#define HH 16
#define CC 40

// ---------------------------------------------------------------------------
// K1: X1 = H @ W1   (N x 512) @ (512 x 16) -> (N x 16)
// One row per thread. W1 reads are wave-uniform -> s_load / SGPR FMA operands.
// H streamed via float4 (per-lane sequential stream, lines fully consumed).
// ---------------------------------------------------------------------------
__global__ __launch_bounds__(256) void k_gemm1(const float* __restrict__ Hm,
                                               const float* __restrict__ W1,
                                               float* __restrict__ X1,
                                               int nrows) {
    int row = blockIdx.x * 256 + (int)threadIdx.x;
    if (row >= nrows) return;
    const float* hp = &Hm[(size_t)row * DD];
    const float4* w4 = reinterpret_cast<const float4*>(W1);  // [DD][4 x float4]

    float acc[HH];
#pragma unroll
    for (int j = 0; j < HH; ++j) acc[j] = 0.f;

    for (int k4 = 0; k4 < DD; k4 += 4) {
        float4 hv = *reinterpret_cast<const float4*>(hp + k4);
        float h[4] = {hv.x, hv.y, hv.z, hv.w};
#pragma unroll
        for (int kk = 0; kk < 4; ++kk) {
#pragma unroll
            for (int j4 = 0; j4 < 4; ++j4) {
                float4 w = w4[(k4 + kk) * 4 + j4];  // wave-uniform -> s_load
                acc[j4 * 4 + 0] += h[kk] * w.x;
                acc[j4 * 4 + 1] += h[kk] * w.y;
                acc[j4 * 4 + 2] += h[kk] * w.z;
                acc[j4 * 4 + 3] += h[kk] * w.w;
            }
        }
    }

    float4* op = reinterpret_cast<float4*>(&X1[(size_t)row * HH]);
#pragma unroll
    for (int j4 = 0; j4 < 4; ++j4)
        op[j4] = make_float4(acc[j4 * 4 + 0], acc[j4 * 4 + 1],
                             acc[j4 * 4 + 2], acc[j4 * 4 + 3]);
}

// ---------------------------------------------------------------------------
// CSR build (every call; no state may persist).
// ---------------------------------------------------------------------------
__global__ __launch_bounds__(256) void k_hist(const int* __restrict__ rows,
                                              int* __restrict__ cnt, int nnz) {
    int e = blockIdx.x * 256 + (int)threadIdx.x;
    if (e < nnz) atomicAdd(&cnt[rows[e]], 1);
}

__global__ __launch_bounds__(256) void k_scan1(const int* __restrict__ cnt,
                                               int* __restrict__ incl,
                                               int* __restrict__ bsum, int n) {
    __shared__ int s[256];
    int i = blockIdx.x * 256 + (int)threadIdx.x;
    int v = (i < n) ? cnt[i] : 0;
    s[threadIdx.x] = v;
    __syncthreads();
    for (int off = 1; off < 256; off <<= 1) {
        int add = (threadIdx.x >= (unsigned)off) ? s[threadIdx.x - off] : 0;
        __syncthreads();
        s[threadIdx.x] += add;
        __syncthreads();
    }
    if (i < n) incl[i] = s[threadIdx.x];
    if (threadIdx.x == 255) bsum[blockIdx.x] = s[255];
}

__global__ __launch_bounds__(512) void k_scan2(int* __restrict__ b, int n2) {
    __shared__ int s[512];
    int i = (int)threadIdx.x;
    s[i] = (i < n2) ? b[i] : 0;
    __syncthreads();
    for (int off = 1; off < 512; off <<= 1) {
        int add = (i >= off) ? s[i - off] : 0;
        __syncthreads();
        s[i] += add;
        __syncthreads();
    }
    if (i < n2) b[i] = s[i];
}

__global__ __launch_bounds__(256) void k_scan3(const int* __restrict__ incl,
                                               const int* __restrict__ bscan,
                                               const int* __restrict__ cnt,
                                               int* __restrict__ row_start,
                                               int* __restrict__ cursor, int n) {
    int i = blockIdx.x * 256 + (int)threadIdx.x;
    if (i >= n) return;
    int prev = (blockIdx.x > 0) ? bscan[blockIdx.x - 1] : 0;
    int inc = incl[i] + prev;
    row_start[i + 1] = inc;
    cursor[i] = inc - cnt[i];
    if (i == 0) row_start[0] = 0;
}

// Packed scatter: one 8-byte (col, val) record per edge -> single dwordx2
// store, halving the random-line-touch count vs two 4B arrays.
__global__ __launch_bounds__(256) void k_scatter(const int* __restrict__ rows,
                                                 const int* __restrict__ cols,
                                                 const float* __restrict__ vals,
                                                 int* __restrict__ cursor,
                                                 int2* __restrict__ epk, int nnz) {
    int e = blockIdx.x * 256 + (int)threadIdx.x;
    if (e >= nnz) return;
    int r = rows[e];
    int slot = atomicAdd(&cursor[r], 1);
    epk[slot] = make_int2(cols[e], __float_as_int(vals[e]));
}

// ---------------------------------------------------------------------------
// Gather spmm, one WAVE per row: lane = j (feature, 0..15) + 16*sub (edge
// stride 0..3). 4-way ILP in the edge loop; shfl_xor reduction over sub.
// row_start reads are wave-uniform -> s_load.
// ---------------------------------------------------------------------------
template <int RELU>
__global__ __launch_bounds__(256) void k_gather(const int* __restrict__ row_start,
                                                const int2* __restrict__ epk,
                                                const float* __restrict__ X,
                                                float* __restrict__ S,
                                                const float* __restrict__ bias,
                                                int nrows) {
    int t = blockIdx.x * 256 + (int)threadIdx.x;
    int r = t >> 6;                 // wave-uniform
    if (r >= nrows) return;
    int lane = (int)threadIdx.x & 63;
    int j = lane & 15;
    int sub = lane >> 4;
    int s = row_start[r];
    int e = row_start[r + 1];
    float bj = RELU ? bias[j] : 0.f;
    float acc = 0.f;
    for (int i = s + sub; i < e; i += 4) {
        int2 cv = epk[i];
        float x = X[(size_t)cv.x * HH + j];
        if (RELU) x = fmaxf(x + bj, 0.f);
        acc += __int_as_float(cv.y) * x;
    }
    acc += __shfl_xor(acc, 16, 64);
    acc += __shfl_xor(acc, 32, 64);
    if (sub == 0) S[(size_t)r * HH + j] = acc;
}

// ---------------------------------------------------------------------------
// Fallback scatter spmm (if ws too small for CSR): thread per (edge, feature).
// ---------------------------------------------------------------------------
__global__ __launch_bounds__(256) void k_spmm(const int* __restrict__ rows,
                                              const int* __restrict__ cols,
                                              const float* __restrict__ vals,
                                              const float* __restrict__ X,
                                              float* __restrict__ S,
                                              const float* __restrict__ bias,
                                              int relu_in, int nnz) {
    long long idx = (long long)blockIdx.x * 256 + threadIdx.x;
    if (idx >= (long long)nnz * HH) return;
    int e = (int)(idx >> 4);
    int j = (int)(idx & 15);
    int c = cols[e];
    int r = rows[e];
    float v = vals[e];
    float x = X[(size_t)c * HH + j];
    if (relu_in) {
        x = fmaxf(x + bias[j], 0.f);
        if (x == 0.f) return;
    }
    atomicAdd(&S[(size_t)r * HH + j], v * x);
}

// ---------------------------------------------------------------------------
// K4: out = log_softmax(relu(T @ W2 + b2)).  One thread per row.
// ---------------------------------------------------------------------------
__global__ __launch_bounds__(256) void k_out(const float* __restrict__ T,
                                             const float* __restrict__ W2,
                                             const float* __restrict__ b2,
                                             float* __restrict__ out,
                                             int nrows) {
    __shared__ float w2s[HH * CC];
    __shared__ float b2s[CC];
    for (int i = (int)threadIdx.x; i < HH * CC; i += 256) w2s[i] = W2[i];
    if (threadIdx.x < CC) b2s[threadIdx.x] = b2[threadIdx.x];
    __syncthreads();

    int row = blockIdx.x * 256 + (int)threadIdx.x;
    if (row >= nrows) return;

    float t[HH];
#pragma unroll
    for (int k4 = 0; k4 < HH; k4 += 4) {
        float4 tv = *reinterpret_cast<const float4*>(&T[(size_t)row * HH + k4]);
        t[k4] = tv.x; t[k4 + 1] = tv.y; t[k4 + 2] = tv.z; t[k4 + 3] = tv.w;
    }

    float y[CC];
#pragma unroll
    for (int j = 0; j < CC; ++j) {
        float a = b2s[j];
#pragma unroll
        for (int k = 0; k < HH; ++k) a += t[k] * w2s[k * CC + j];
        y[j] = a > 0.f ? a : 0.f;
    }

    float m = y[0];
#pragma unroll
    for (int j = 1; j < CC; ++j) m = fmaxf(m, y[j]);
    float s = 0.f;
#pragma unroll
    for (int j = 0; j < CC; ++j) s += __expf(y[j] - m);
    float ls = __logf(s) + m;

    float4* op = reinterpret_cast<float4*>(&out[(size_t)row * CC]);
#pragma unroll
    for (int j4 = 0; j4 < CC / 4; ++j4)
        op[j4] = make_float4(y[j4 * 4 + 0] - ls, y[j4 * 4 + 1] - ls,
                             y[j4 * 4 + 2] - ls, y[j4 * 4 + 3] - ls);
}

// ---------------------------------------------------------------------------
extern "C" void kernel_launch(void* const* d_in, const int* in_sizes, int n_in,
                              void* d_out, int out_size, void* d_ws, size_t ws_size,
                              hipStream_t stream) {
    const float* Hm = (const float*)d_in[0];
    const float* Av = (const float*)d_in[1];
    const float* W1 = (const float*)d_in[2];
    const float* b1 = (const float*)d_in[3];
    const float* W2 = (const float*)d_in[4];
    const float* b2 = (const float*)d_in[5];
    const int*   Ar = (const int*)d_in[6];
    const int*   Ac = (const int*)d_in[7];
    float*       out = (float*)d_out;

    const int N   = in_sizes[0] / DD;
    const int NNZ = in_sizes[6];

    // workspace layout
    char* ws = (char*)d_ws;
    size_t off = 0;
    float* X1 = (float*)(ws + off); off += (size_t)N * HH * 4;
    float* S1 = (float*)(ws + off); off += (size_t)N * HH * 4;
    float* T  = (float*)(ws + off); off += (size_t)N * HH * 4;
    int* cnt       = (int*)(ws + off); off += (size_t)N * 4;
    int* incl      = (int*)(ws + off); off += (size_t)N * 4;
    int* bsum      = (int*)(ws + off); off += 512 * 4;
    int* row_start = (int*)(ws + off); off += (size_t)(N + 1) * 4;
    int* cursor    = (int*)(ws + off); off += (size_t)N * 4;
    off = (off + 15) & ~(size_t)15;
    int2* epk      = (int2*)(ws + off); off += (size_t)NNZ * 8;
    const bool csr_ok = (off <= ws_size);

    // K1: X1 = H @ W1
    k_gemm1<<<(N + 255) / 256, 256, 0, stream>>>(Hm, W1, X1, N);

    const int gE = (NNZ + 255) / 256;
    const int gR = (N + 255) / 256;

    if (csr_ok) {
        hipMemsetAsync(cnt, 0, (size_t)N * 4, stream);
        k_hist<<<gE, 256, 0, stream>>>(Ar, cnt, NNZ);
        k_scan1<<<gR, 256, 0, stream>>>(cnt, incl, bsum, N);
        k_scan2<<<1, 512, 0, stream>>>(bsum, gR);
        k_scan3<<<gR, 256, 0, stream>>>(incl, bsum, cnt, row_start, cursor, N);
        k_scatter<<<gE, 256, 0, stream>>>(Ar, Ac, Av, cursor, epk, NNZ);

        // wave-per-row gathers (4 rows per 256-thread block)
        int gG = (N + 3) / 4;
        k_gather<0><<<gG, 256, 0, stream>>>(row_start, epk, X1, S1, b1, N);
        k_gather<1><<<gG, 256, 0, stream>>>(row_start, epk, S1, T, b1, N);
    } else {
        hipMemsetAsync(S1, 0, (size_t)2 * N * HH * 4, stream);
        long long work = (long long)NNZ * HH;
        int g2 = (int)((work + 255) / 256);
        k_spmm<<<g2, 256, 0, stream>>>(Ar, Ac, Av, X1, S1, b1, 0, NNZ);
        k_spmm<<<g2, 256, 0, stream>>>(Ar, Ac, Av, S1, T, b1, 1, NNZ);
    }

    k_out<<<gR, 256, 0, stream>>>(T, W2, b2, out, N);
}